// Round 16
// baseline (135.076 us; speedup 1.0000x reference)
//
#include <hip/hip_runtime.h>

#define NB 8
#define NN 2048
#define NM 8192
#define NC 64
#define ND 64
#define NK 16

#define PARTS 8     // lanes per query
#define PPT 256     // points per lane (NN / PARTS)
#define HCHUNK 264  // padded chunk stride in HALFS: 528 B = 33*16 (aligned
                    // b128 blocks); 132 mod 32 = 4 -> chunks on distinct
                    // bank-quads for pass-1 broadcast reads
#define QPB 32      // queries per block (256 threads / 8 parts)
#define NG 8        // groups of 32 points per lane
#define CAP 64      // candidate slots per query
#define CSTR 66     // cand row stride in u16

#define KB (NM / QPB)       // knn blocks per batch (256) -- FIRST in grid
#define FB (NN / 64)        // feats blocks per batch (32) -- after knn
#define SMEM_BYTES 17408    // knn: 3*8*264*2 + 32*66*2 + 128 = 17024
                            // feats tile = 64*68*4 = 17408 -> union 17408
                            // -> 8 blocks/CU (32 waves/CU, max occupancy)
// r8/r9: 512-thread blocks regress ~17% even without spills.
// r10: packed dist8p freed VALU but time flat. r11: parallel phase 3
// 120->73.5us. r12: batched atomics. r13: swizzle (conflicts -32%).
// r14: single barrier. r15: FMA screening + guarded threshold (-6us).
// r16: f16 SCREENING store -- points LDS 24.9->12.7KB -> 8 blocks/CU;
//      3 ds_read_b128 per 8-pt block (was 6); guard widened to 1.01.
//      Phase-3/output read exact f32 coords from global (L1/L2-hot).

typedef __attribute__((ext_vector_type(2))) _Float16 h2;
typedef __attribute__((ext_vector_type(8))) _Float16 h8;

// physical LDS slot (in halfs) of logical point index i (0..2047)
__device__ __forceinline__ int slotOf(int i) {
  const int B = (i & 255) >> 3;        // logical 8-pt block in chunk
  const int BS = B ^ (B >> 2);         // bank-swizzled block
  return (i >> 8) * HCHUNK + (BS << 3) + (i & 7);
}

__device__ __forceinline__ float d2rn(float qx, float qy, float qz, float x,
                                      float y, float z) {
  const float dx = __fsub_rn(qx, x);
  const float dy = __fsub_rn(qy, y);
  const float dz = __fsub_rn(qz, z);
  return __fadd_rn(__fadd_rn(__fmul_rn(dx, dx), __fmul_rn(dy, dy)),
                   __fmul_rn(dz, dz));
}

#define CE(a, i, j)                     \
  {                                     \
    const float lo = fminf(a[i], a[j]); \
    const float hi = fmaxf(a[i], a[j]); \
    a[i] = lo;                          \
    a[j] = hi;                          \
  }

// u64 compare-exchange (ascending)
#define CEU(a, i, j)                                      \
  {                                                       \
    const bool c_ = a[i] < a[j];                          \
    const unsigned long long lo_ = c_ ? a[i] : a[j];      \
    const unsigned long long hi_ = c_ ? a[j] : a[i];      \
    a[i] = lo_;                                           \
    a[j] = hi_;                                           \
  }

// Batcher odd-even sort of d[8] ascending (19 comparators) -- float
#define SORT8(d)                                  \
  CE(d, 0, 1) CE(d, 2, 3) CE(d, 4, 5) CE(d, 6, 7) \
  CE(d, 0, 2) CE(d, 1, 3) CE(d, 4, 6) CE(d, 5, 7) \
  CE(d, 1, 2) CE(d, 5, 6)                         \
  CE(d, 0, 4) CE(d, 1, 5) CE(d, 2, 6) CE(d, 3, 7) \
  CE(d, 2, 4) CE(d, 3, 5)                         \
  CE(d, 1, 2) CE(d, 3, 4) CE(d, 5, 6)

// Batcher odd-even sort of u64[8] ascending (19 comparators)
#define SORT8U(d)                                          \
  CEU(d, 0, 1) CEU(d, 2, 3) CEU(d, 4, 5) CEU(d, 6, 7)      \
  CEU(d, 0, 2) CEU(d, 1, 3) CEU(d, 4, 6) CEU(d, 5, 7)      \
  CEU(d, 1, 2) CEU(d, 5, 6)                                \
  CEU(d, 0, 4) CEU(d, 1, 5) CEU(d, 2, 6) CEU(d, 3, 7)      \
  CEU(d, 2, 4) CEU(d, 3, 5)                                \
  CEU(d, 1, 2) CEU(d, 3, 4) CEU(d, 5, 6)

// bitonic-8 sorter (input must be bitonic) -- u64, 12 comparators
#define BSORT8U(d)                                         \
  CEU(d, 0, 4) CEU(d, 1, 5) CEU(d, 2, 6) CEU(d, 3, 7)      \
  CEU(d, 0, 2) CEU(d, 1, 3) CEU(d, 4, 6) CEU(d, 5, 7)      \
  CEU(d, 0, 1) CEU(d, 2, 3) CEU(d, 4, 5) CEU(d, 6, 7)

// bitonic sort of L[16] (input bitonic) ascending: 32 comparators -- float
#define BITONIC16(L)                                                      \
  CE(L, 0, 8) CE(L, 1, 9) CE(L, 2, 10) CE(L, 3, 11) CE(L, 4, 12)          \
  CE(L, 5, 13) CE(L, 6, 14) CE(L, 7, 15)                                  \
  CE(L, 0, 4) CE(L, 1, 5) CE(L, 2, 6) CE(L, 3, 7) CE(L, 8, 12)            \
  CE(L, 9, 13) CE(L, 10, 14) CE(L, 11, 15)                                \
  CE(L, 0, 2) CE(L, 1, 3) CE(L, 4, 6) CE(L, 5, 7) CE(L, 8, 10)            \
  CE(L, 9, 11) CE(L, 12, 14) CE(L, 13, 15)                                \
  CE(L, 0, 1) CE(L, 2, 3) CE(L, 4, 5) CE(L, 6, 7) CE(L, 8, 9)             \
  CE(L, 10, 11) CE(L, 12, 13) CE(L, 14, 15)

// f16 packed-pair screening distance: 8 points -> 4 h2 of approx d^2.
// 3 ds_read_b128 per 8 points (was 6 in f32). v_pk_*_f16 ops.
// Used ONLY for candidate filtering with Te = T*1.01 guard.
__device__ __forceinline__ void dist8h(const _Float16* hx, const _Float16* hy,
                                       const _Float16* hz, int base, h2 qvx,
                                       h2 qvy, h2 qvz, h2 dd[4]) {
  const h8 X = *(const h8*)&hx[base];
  const h8 Y = *(const h8*)&hy[base];
  const h8 Z = *(const h8*)&hz[base];
#pragma unroll
  for (int k = 0; k < 4; k++) {
    const h2 xk = {X[2 * k], X[2 * k + 1]};
    const h2 yk = {Y[2 * k], Y[2 * k + 1]};
    const h2 zk = {Z[2 * k], Z[2 * k + 1]};
    const h2 dx = qvx - xk, dy = qvy - yk, dz = qvz - zk;
    dd[k] = __builtin_elementwise_fma(
        dz, dz, __builtin_elementwise_fma(dy, dy, dx * dx));
  }
}

__device__ __forceinline__ float min8h(const h2 dd[4]) {
  const h2 m = __builtin_elementwise_min(
      __builtin_elementwise_min(dd[0], dd[1]),
      __builtin_elementwise_min(dd[2], dd[3]));
  return fminf((float)m[0], (float)m[1]);
}

// ---------------------------------------------------------------------------
// Fused kernel (r15 structure); delta: f16 screening store (8 blocks/CU),
// Te guard 1.01, phase-3/output coords from global xyz.
// ---------------------------------------------------------------------------
__global__ __launch_bounds__(256, 4) void fused_kernel(
    const float* __restrict__ features, const float* __restrict__ W1,
    const float* __restrict__ b1, float* __restrict__ out_feats,
    float* __restrict__ out_x, const float* __restrict__ xyz,
    const float* __restrict__ xyz_fp, float* __restrict__ out_knn) {
  __shared__ __align__(16) unsigned char smem[SMEM_BYTES];

  const int b = blockIdx.y;
  const int t = threadIdx.x;

  if (blockIdx.x >= KB) {
    // ================= feats + linear path (verbatim r7) =================
    float(*tile)[68] = reinterpret_cast<float(*)[68]>(smem);  // 17408 B

    const int n0 = (blockIdx.x - KB) * 64;
    const int lane = t & 63;
    const int grp = t >> 6;

    for (int c = grp; c < NC; c += 4)
      tile[c][lane] = features[((size_t)(b * NC + c) * NN) + n0 + lane];

    float4 wreg[16];
    {
      const float4* Wr = (const float4*)(W1 + lane * NC);
#pragma unroll
      for (int k = 0; k < 16; k++) wreg[k] = Wr[k];
    }
    __syncthreads();

    for (int j = grp; j < 64; j += 4)
      out_feats[((size_t)(b * NN + n0 + j) * NC) + lane] = tile[lane][j];

    const int d = lane;
    float acc[16];
    const float bd = b1[d];
#pragma unroll
    for (int jj = 0; jj < 16; jj++) acc[jj] = bd;

    const float4* tv = (const float4*)&tile[0][0];
#pragma unroll
    for (int k = 0; k < 16; k++) {
#pragma unroll
      for (int cc = 0; cc < 4; cc++) {
        const int c = k * 4 + cc;
        const float w = (cc == 0)   ? wreg[k].x
                        : (cc == 1) ? wreg[k].y
                        : (cc == 2) ? wreg[k].z
                                    : wreg[k].w;
#pragma unroll
        for (int q = 0; q < 4; q++) {
          const float4 v = tv[c * 17 + grp * 4 + q];
          acc[q * 4 + 0] = fmaf(v.x, w, acc[q * 4 + 0]);
          acc[q * 4 + 1] = fmaf(v.y, w, acc[q * 4 + 1]);
          acc[q * 4 + 2] = fmaf(v.z, w, acc[q * 4 + 2]);
          acc[q * 4 + 3] = fmaf(v.w, w, acc[q * 4 + 3]);
        }
      }
    }
#pragma unroll
    for (int jj = 0; jj < 16; jj++) {
      const int j = grp * 16 + jj;
      out_x[((size_t)(b * NN + n0 + j) * ND) + d] = acc[jj];
    }
    return;
  }

  // ======================= kNN path =======================
  _Float16* hx = reinterpret_cast<_Float16*>(smem);
  _Float16* hy = hx + PARTS * HCHUNK;
  _Float16* hz = hy + PARTS * HCHUNK;
  unsigned short* cand =
      reinterpret_cast<unsigned short*>(smem + 3 * PARTS * HCHUNK * 2);
  int* ccnt =
      reinterpret_cast<int*>(smem + 3 * PARTS * HCHUNK * 2 + QPB * CSTR * 2);

  const int ql = t >> 3;   // query-local 0..31 (lanes ql*8..ql*8+7: one wave)
  const int part = t & 7;  // 0..7

  if (t < QPB) ccnt[t] = 0;

  // stage points as f16 into swizzled slots (screening store)
  const float* P = xyz + (size_t)b * NN * 3;
  for (int i = t; i < NN; i += 256) {
    const int slot = slotOf(i);
    hx[slot] = (_Float16)P[3 * i + 0];
    hy[slot] = (_Float16)P[3 * i + 1];
    hz[slot] = (_Float16)P[3 * i + 2];
  }
  __syncthreads();  // the ONLY block barrier

  const int q = blockIdx.x * QPB + ql;
  const float* Q = xyz_fp + ((size_t)b * NM + q) * 3;
  const float qx = Q[0], qy = Q[1], qz = Q[2];
  const _Float16 qhx = (_Float16)qx, qhy = (_Float16)qy, qhz = (_Float16)qz;
  const h2 qvx = {qhx, qhx}, qvy = {qhy, qhy}, qvz = {qhz, qhz};

  const int pbase = part * HCHUNK;

  // ---- pass 1: group mins (f16 metric, packed min tree) ----
  float gmin[NG];
#pragma unroll
  for (int g = 0; g < NG; g++) {
    h2 gm2 = {(_Float16)6.0e4f, (_Float16)6.0e4f};
#pragma unroll
    for (int bb = 0; bb < 4; bb++) {
      const int B = g * 4 + bb;
      const int BS = B ^ (B >> 2);
      h2 dd[4];
      dist8h(hx, hy, hz, pbase + BS * 8, qvx, qvy, qvz, dd);
      gm2 = __builtin_elementwise_min(
          gm2, __builtin_elementwise_min(
                   __builtin_elementwise_min(dd[0], dd[1]),
                   __builtin_elementwise_min(dd[2], dd[3])));
    }
    gmin[g] = fminf((float)gm2[0], (float)gm2[1]);
  }

  // ---- T = 16th-smallest of the query's 64 group-mins (f16 metric) ----
  float s[16];
  {
    float g8[NG];
#pragma unroll
    for (int g = 0; g < NG; g++) g8[g] = gmin[g];
    SORT8(g8)
#pragma unroll
    for (int j = 0; j < 8; j++) s[j] = g8[j];
#pragma unroll
    for (int j = 8; j < 16; j++) s[j] = 3.0e38f;
  }
#pragma unroll
  for (int mask = 1; mask <= 4; mask <<= 1) {
    float B[16];
#pragma unroll
    for (int j = 0; j < 16; j++) B[j] = __shfl_xor(s[j], mask, 64);
    float L[16];
#pragma unroll
    for (int j = 0; j < 16; j++) L[j] = fminf(s[j], B[15 - j]);
    BITONIC16(L)
#pragma unroll
    for (int j = 0; j < 16; j++) s[j] = L[j];
  }
  // guard: f16 inputs + 6-op f16 arithmetic skew <= ~4e-3 relative;
  // superset proof needs (1+4e-3)^2 < 1.01. Phase-3 d2rn stays exact.
  const float Te = s[15] * 1.01f;

  // ---- per-lane 8-bit pass mask ----
  unsigned m8 = 0;
#pragma unroll
  for (int g = 0; g < NG; g++) m8 |= (gmin[g] <= Te) ? (1u << g) : 0u;

  // ---- butterfly-OR across the query's 8 lanes -> 64-bit group mask ----
  unsigned lo = (part < 4) ? (m8 << (8 * part)) : 0u;
  unsigned hi = (part >= 4) ? (m8 << (8 * (part - 4))) : 0u;
#pragma unroll
  for (int mk = 1; mk <= 4; mk <<= 1) {
    lo |= __shfl_xor(lo, mk, 64);
    hi |= __shfl_xor(hi, mk, 64);
  }
  const unsigned long long vm = ((unsigned long long)hi << 32) | lo;

  // ---- round-robin: k-th set bit -> lane (k & 7) ----
  unsigned long long mym = 0ull;
  {
    unsigned long long m = vm;
    int cnt = 0;
    while (m) {
      const unsigned long long lb = m & (0ull - m);
      if ((cnt & 7) == part) mym |= lb;
      m ^= lb;
      cnt++;
    }
  }

  // ---- pass 2: scan assigned groups; batched slot reservation ----
  while (mym) {
    const int gid = __ffsll(mym) - 1;
    mym &= mym - 1;
    const int cb = (gid >> 3) * HCHUNK;
    const int goff = gid & 7;
    const int ib = (gid >> 3) * PPT + goff * 32;
#pragma unroll
    for (int bb = 0; bb < 4; bb++) {
      const int B = goff * 4 + bb;
      const int BS = B ^ (B >> 2);
      h2 dd[4];
      dist8h(hx, hy, hz, cb + BS * 8, qvx, qvy, qvz, dd);
      if (min8h(dd) <= Te) {
        unsigned am = 0;
#pragma unroll
        for (int k = 0; k < 4; k++) {
          am |= ((float)dd[k][0] <= Te) ? (1u << (2 * k)) : 0u;
          am |= ((float)dd[k][1] <= Te) ? (1u << (2 * k + 1)) : 0u;
        }
        int pos = atomicAdd(&ccnt[ql], __popc(am));
        while (am) {
          const int k = __ffs(am) - 1;
          am &= am - 1;
          if (pos < CAP)
            cand[ql * CSTR + pos] = (unsigned short)(ib + bb * 8 + k);
          pos++;
        }
      }
    }
  }
  // NO barrier: phase 3 reads only this wave's writes

  // ---- phase 3: exact top-16 (d2rn on GLOBAL f32 coords), 8-lane ----
  {
    const int cnt = ccnt[ql];
    if (cnt <= CAP) {
      unsigned long long kb8[8];
#pragma unroll
      for (int i = 0; i < 8; i++) {
        const int c = part + 8 * i;
        unsigned long long kk = ~0ULL;
        if (c < cnt) {
          const int idx = cand[ql * CSTR + c];
          const float d2 = d2rn(qx, qy, qz, P[3 * idx], P[3 * idx + 1],
                                P[3 * idx + 2]);
          kk = ((unsigned long long)__float_as_uint(d2) << 32) | (unsigned)idx;
        }
        kb8[i] = kk;
      }
      SORT8U(kb8)

      // round 1 (XOR 1): pair merge -> sorted-16 per lane pair
      {
        unsigned long long bb[8];
#pragma unroll
        for (int j = 0; j < 8; j++) bb[j] = __shfl_xor(kb8[7 - j], 1, 64);
        if (part & 1) {
#pragma unroll
          for (int j = 0; j < 8; j++)
            kb8[j] = (kb8[j] < bb[j]) ? bb[j] : kb8[j];
        } else {
#pragma unroll
          for (int j = 0; j < 8; j++)
            kb8[j] = (kb8[j] < bb[j]) ? kb8[j] : bb[j];
        }
        BSORT8U(kb8)
      }

      // rounds 2,3 (XOR 3 then XOR 5): merge sorted-16s, keep top-16
#pragma unroll
      for (int r = 0; r < 2; r++) {
        const int xm = r ? 5 : 3;
        unsigned long long bb[8];
#pragma unroll
        for (int j = 0; j < 8; j++) bb[j] = __shfl_xor(kb8[7 - j], xm, 64);
#pragma unroll
        for (int j = 0; j < 8; j++)
          kb8[j] = (kb8[j] < bb[j]) ? kb8[j] : bb[j];
#pragma unroll
        for (int j = 0; j < 8; j++) bb[j] = __shfl_xor(kb8[j], 1, 64);
        if (part & 1) {
#pragma unroll
          for (int j = 0; j < 8; j++)
            kb8[j] = (kb8[j] < bb[j]) ? bb[j] : kb8[j];
        } else {
#pragma unroll
          for (int j = 0; j < 8; j++)
            kb8[j] = (kb8[j] < bb[j]) ? kb8[j] : bb[j];
        }
        BSORT8U(kb8)
      }

      // final sorted-16: even lane holds ranks 0-7, odd lane ranks 8-15
      if (part < 2) {
#pragma unroll
        for (int j = 0; j < 8; j++)
          cand[ql * CSTR + part * 8 + j] = (unsigned short)(unsigned)kb8[j];
      }
    } else if (part == 0) {
      // overflow fallback (astronomically rare): serial exact scan (global)
      unsigned long long kb[NK];
#pragma unroll
      for (int j = 0; j < NK; j++) kb[j] = ~0ULL;
      for (int i = 0; i < NN; i++) {
        const float d2 =
            d2rn(qx, qy, qz, P[3 * i], P[3 * i + 1], P[3 * i + 2]);
        unsigned long long kk =
            ((unsigned long long)__float_as_uint(d2) << 32) | (unsigned)i;
        if (kk < kb[NK - 1]) {
#pragma unroll
          for (int j = 0; j < NK; j++) {
            const bool c2 = kk < kb[j];
            const unsigned long long lo2 = c2 ? kk : kb[j];
            const unsigned long long hi2 = c2 ? kb[j] : kk;
            kb[j] = lo2;
            kk = hi2;
          }
        }
      }
#pragma unroll
      for (int j = 0; j < NK; j++)
        cand[ql * CSTR + j] = (unsigned short)(unsigned)kb[j];
    }
  }
  // NO barrier: output reads only this wave's phase-3 writes

  // ---- output: each part lane writes 2 neighbors (f32 from global) ----
  float* o = out_knn + ((size_t)(b * NM + q)) * (NK * 3);
#pragma unroll
  for (int jj = 0; jj < 2; jj++) {
    const int j = part * 2 + jj;
    const int i = cand[ql * CSTR + j];
    o[3 * j + 0] = P[3 * i + 0];
    o[3 * j + 1] = P[3 * i + 1];
    o[3 * j + 2] = P[3 * i + 2];
  }
}

// ---------------------------------------------------------------------------
extern "C" void kernel_launch(void* const* d_in, const int* in_sizes, int n_in,
                              void* d_out, int out_size, void* d_ws,
                              size_t ws_size, hipStream_t stream) {
  const float* xyz      = (const float*)d_in[0];  // [8,2048,3]
  const float* xyz_fp   = (const float*)d_in[1];  // [8,8192,3]
  const float* features = (const float*)d_in[2];  // [8,64,2048]
  const float* W1 = (const float*)d_in[4];        // [64,64]
  const float* b1 = (const float*)d_in[5];        // [64]

  float* out_feats = (float*)d_out;                       // 8*2048*64
  float* out_knn   = out_feats + (size_t)NB * NN * NC;    // 8*8192*16*3
  float* out_x     = out_knn + (size_t)NB * NM * NK * 3;  // 8*2048*64

  fused_kernel<<<dim3(KB + FB, NB), 256, 0, stream>>>(
      features, W1, b1, out_feats, out_x, xyz, xyz_fp, out_knn);
}

// Round 18
// 131.403 us; speedup vs baseline: 1.0280x; 1.0280x over previous
//
#include <hip/hip_runtime.h>

#define NB 8
#define NN 2048
#define NM 8192
#define NC 64
#define ND 64
#define NK 16

#define PARTS 8     // lanes per query
#define PPT 256     // points per lane (NN / PARTS)
#define CHUNK 260   // padded chunk stride in floats
#define QPB 32      // queries per block (256 threads / 8 parts)
#define NG 8        // groups of 32 points per lane
#define CAP 64      // candidate slots per query
#define CSTR 66     // cand row stride in u16

#define KB (NM / QPB)       // knn blocks per batch (256) -- FIRST in grid
#define FB (NN / 64)        // feats blocks per batch (32) -- after knn
#define SMEM_BYTES 29312    // knn: 3*8*260*4 + 32*66*2 + 32*4 = 29312 (5/CU)
// r8/r9: 512-thread blocks regress ~17% even without spills.
// r10: packed dist8p freed VALU but time flat. r11: parallel phase 3
// 120->73.5us. r12: batched atomics. r13: swizzle (conflicts -32%).
// r14: single barrier. r15: FMA screening + guarded threshold (-6us).
// r16: f16 screen halved LDS reads BUT phase-3/output global gathers
//      regressed bench +4.2us -> REVERTED to r15.
// r17: infra failure (no data). This file = r15 verbatim, A/B retry.

typedef __attribute__((ext_vector_type(2))) float f2;
typedef __attribute__((ext_vector_type(4))) float f4;

// physical LDS slot of logical point index i (0..2047)
__device__ __forceinline__ int slotOf(int i) {
  const int B = (i & 255) >> 3;        // logical block in chunk
  const int BS = B ^ (B >> 2);         // bank-swizzled block
  return (i >> 8) * CHUNK + (BS << 3) + (i & 7);
}

__device__ __forceinline__ float d2rn(float qx, float qy, float qz, float x,
                                      float y, float z) {
  const float dx = __fsub_rn(qx, x);
  const float dy = __fsub_rn(qy, y);
  const float dz = __fsub_rn(qz, z);
  return __fadd_rn(__fadd_rn(__fmul_rn(dx, dx), __fmul_rn(dy, dy)),
                   __fmul_rn(dz, dz));
}

#define CE(a, i, j)                     \
  {                                     \
    const float lo = fminf(a[i], a[j]); \
    const float hi = fmaxf(a[i], a[j]); \
    a[i] = lo;                          \
    a[j] = hi;                          \
  }

// u64 compare-exchange (ascending)
#define CEU(a, i, j)                                      \
  {                                                       \
    const bool c_ = a[i] < a[j];                          \
    const unsigned long long lo_ = c_ ? a[i] : a[j];      \
    const unsigned long long hi_ = c_ ? a[j] : a[i];      \
    a[i] = lo_;                                           \
    a[j] = hi_;                                           \
  }

// Batcher odd-even sort of d[8] ascending (19 comparators) -- float
#define SORT8(d)                                  \
  CE(d, 0, 1) CE(d, 2, 3) CE(d, 4, 5) CE(d, 6, 7) \
  CE(d, 0, 2) CE(d, 1, 3) CE(d, 4, 6) CE(d, 5, 7) \
  CE(d, 1, 2) CE(d, 5, 6)                         \
  CE(d, 0, 4) CE(d, 1, 5) CE(d, 2, 6) CE(d, 3, 7) \
  CE(d, 2, 4) CE(d, 3, 5)                         \
  CE(d, 1, 2) CE(d, 3, 4) CE(d, 5, 6)

// Batcher odd-even sort of u64[8] ascending (19 comparators)
#define SORT8U(d)                                          \
  CEU(d, 0, 1) CEU(d, 2, 3) CEU(d, 4, 5) CEU(d, 6, 7)      \
  CEU(d, 0, 2) CEU(d, 1, 3) CEU(d, 4, 6) CEU(d, 5, 7)      \
  CEU(d, 1, 2) CEU(d, 5, 6)                                \
  CEU(d, 0, 4) CEU(d, 1, 5) CEU(d, 2, 6) CEU(d, 3, 7)      \
  CEU(d, 2, 4) CEU(d, 3, 5)                                \
  CEU(d, 1, 2) CEU(d, 3, 4) CEU(d, 5, 6)

// bitonic-8 sorter (input must be bitonic) -- u64, 12 comparators
#define BSORT8U(d)                                         \
  CEU(d, 0, 4) CEU(d, 1, 5) CEU(d, 2, 6) CEU(d, 3, 7)      \
  CEU(d, 0, 2) CEU(d, 1, 3) CEU(d, 4, 6) CEU(d, 5, 7)      \
  CEU(d, 0, 1) CEU(d, 2, 3) CEU(d, 4, 5) CEU(d, 6, 7)

// bitonic sort of L[16] (input bitonic) ascending: 32 comparators -- float
#define BITONIC16(L)                                                      \
  CE(L, 0, 8) CE(L, 1, 9) CE(L, 2, 10) CE(L, 3, 11) CE(L, 4, 12)          \
  CE(L, 5, 13) CE(L, 6, 14) CE(L, 7, 15)                                  \
  CE(L, 0, 4) CE(L, 1, 5) CE(L, 2, 6) CE(L, 3, 7) CE(L, 8, 12)            \
  CE(L, 9, 13) CE(L, 10, 14) CE(L, 11, 15)                                \
  CE(L, 0, 2) CE(L, 1, 3) CE(L, 4, 6) CE(L, 5, 7) CE(L, 8, 10)            \
  CE(L, 9, 11) CE(L, 12, 14) CE(L, 13, 15)                                \
  CE(L, 0, 1) CE(L, 2, 3) CE(L, 4, 5) CE(L, 6, 7) CE(L, 8, 9)             \
  CE(L, 10, 11) CE(L, 12, 13) CE(L, 14, 15)

// FMA packed-pair distance: 8 points -> 4 f2 of d^2 approx. 6 pk-ops/pair
// (3 sub, 1 mul, 2 fma -> v_pk_fma_f32). Used ONLY for candidate filtering
// with an inflated threshold; exact ordering uses d2rn in phase 3.
__device__ __forceinline__ void dist8f(const float* px, const float* py,
                                       const float* pz, int base, float qx,
                                       float qy, float qz, f2 dd[4]) {
  const f4 X0 = *(const f4*)&px[base];
  const f4 X1 = *(const f4*)&px[base + 4];
  const f4 Y0 = *(const f4*)&py[base];
  const f4 Y1 = *(const f4*)&py[base + 4];
  const f4 Z0 = *(const f4*)&pz[base];
  const f4 Z1 = *(const f4*)&pz[base + 4];
  const f2 qvx = {qx, qx}, qvy = {qy, qy}, qvz = {qz, qz};
  {
    const f2 dx = qvx - X0.xy, dy = qvy - Y0.xy, dz = qvz - Z0.xy;
    dd[0] = __builtin_elementwise_fma(
        dz, dz, __builtin_elementwise_fma(dy, dy, dx * dx));
  }
  {
    const f2 dx = qvx - X0.zw, dy = qvy - Y0.zw, dz = qvz - Z0.zw;
    dd[1] = __builtin_elementwise_fma(
        dz, dz, __builtin_elementwise_fma(dy, dy, dx * dx));
  }
  {
    const f2 dx = qvx - X1.xy, dy = qvy - Y1.xy, dz = qvz - Z1.xy;
    dd[2] = __builtin_elementwise_fma(
        dz, dz, __builtin_elementwise_fma(dy, dy, dx * dx));
  }
  {
    const f2 dx = qvx - X1.zw, dy = qvy - Y1.zw, dz = qvz - Z1.zw;
    dd[3] = __builtin_elementwise_fma(
        dz, dz, __builtin_elementwise_fma(dy, dy, dx * dx));
  }
}

__device__ __forceinline__ float min8p(const f2 dd[4]) {
  return fminf(fminf(fminf(dd[0].x, dd[0].y), fminf(dd[1].x, dd[1].y)),
               fminf(fminf(dd[2].x, dd[2].y), fminf(dd[3].x, dd[3].y)));
}

// ---------------------------------------------------------------------------
// Fused kernel (r15 verbatim): FMA distances in pass 1/2 with threshold
// inflated by (1+4e-6). Phase 3 exact d2rn from LDS. Single barrier.
// ---------------------------------------------------------------------------
__global__ __launch_bounds__(256, 4) void fused_kernel(
    const float* __restrict__ features, const float* __restrict__ W1,
    const float* __restrict__ b1, float* __restrict__ out_feats,
    float* __restrict__ out_x, const float* __restrict__ xyz,
    const float* __restrict__ xyz_fp, float* __restrict__ out_knn) {
  __shared__ __align__(16) unsigned char smem[SMEM_BYTES];

  const int b = blockIdx.y;
  const int t = threadIdx.x;

  if (blockIdx.x >= KB) {
    // ================= feats + linear path (verbatim r7) =================
    float(*tile)[68] = reinterpret_cast<float(*)[68]>(smem);  // 17408 B

    const int n0 = (blockIdx.x - KB) * 64;
    const int lane = t & 63;
    const int grp = t >> 6;

    for (int c = grp; c < NC; c += 4)
      tile[c][lane] = features[((size_t)(b * NC + c) * NN) + n0 + lane];

    float4 wreg[16];
    {
      const float4* Wr = (const float4*)(W1 + lane * NC);
#pragma unroll
      for (int k = 0; k < 16; k++) wreg[k] = Wr[k];
    }
    __syncthreads();

    for (int j = grp; j < 64; j += 4)
      out_feats[((size_t)(b * NN + n0 + j) * NC) + lane] = tile[lane][j];

    const int d = lane;
    float acc[16];
    const float bd = b1[d];
#pragma unroll
    for (int jj = 0; jj < 16; jj++) acc[jj] = bd;

    const float4* tv = (const float4*)&tile[0][0];
#pragma unroll
    for (int k = 0; k < 16; k++) {
#pragma unroll
      for (int cc = 0; cc < 4; cc++) {
        const int c = k * 4 + cc;
        const float w = (cc == 0)   ? wreg[k].x
                        : (cc == 1) ? wreg[k].y
                        : (cc == 2) ? wreg[k].z
                                    : wreg[k].w;
#pragma unroll
        for (int q = 0; q < 4; q++) {
          const float4 v = tv[c * 17 + grp * 4 + q];
          acc[q * 4 + 0] = fmaf(v.x, w, acc[q * 4 + 0]);
          acc[q * 4 + 1] = fmaf(v.y, w, acc[q * 4 + 1]);
          acc[q * 4 + 2] = fmaf(v.z, w, acc[q * 4 + 2]);
          acc[q * 4 + 3] = fmaf(v.w, w, acc[q * 4 + 3]);
        }
      }
    }
#pragma unroll
    for (int jj = 0; jj < 16; jj++) {
      const int j = grp * 16 + jj;
      out_x[((size_t)(b * NN + n0 + j) * ND) + d] = acc[jj];
    }
    return;
  }

  // ======================= kNN path =======================
  float* px = reinterpret_cast<float*>(smem);
  float* py = px + PARTS * CHUNK;
  float* pz = py + PARTS * CHUNK;
  unsigned short* cand =
      reinterpret_cast<unsigned short*>(smem + 3 * PARTS * CHUNK * 4);
  int* ccnt =
      reinterpret_cast<int*>(smem + 3 * PARTS * CHUNK * 4 + QPB * CSTR * 2);

  const int ql = t >> 3;   // query-local 0..31 (lanes ql*8..ql*8+7: one wave)
  const int part = t & 7;  // 0..7

  if (t < QPB) ccnt[t] = 0;

  // stage points SoA into swizzled slots
  const float* P = xyz + (size_t)b * NN * 3;
  for (int i = t; i < NN; i += 256) {
    const int slot = slotOf(i);
    px[slot] = P[3 * i + 0];
    py[slot] = P[3 * i + 1];
    pz[slot] = P[3 * i + 2];
  }
  __syncthreads();  // the ONLY block barrier: staging + ccnt init visibility

  const int q = blockIdx.x * QPB + ql;
  const float* Q = xyz_fp + ((size_t)b * NM + q) * 3;
  const float qx = Q[0], qy = Q[1], qz = Q[2];

  const int pbase = part * CHUNK;

  // ---- pass 1: group mins (FMA metric) ----
  float gmin[NG];
#pragma unroll
  for (int g = 0; g < NG; g++) {
    float gm = 3.0e38f;
#pragma unroll
    for (int bb = 0; bb < 4; bb++) {
      const int B = g * 4 + bb;
      const int BS = B ^ (B >> 2);
      f2 dd[4];
      dist8f(px, py, pz, pbase + BS * 8, qx, qy, qz, dd);
      gm = fminf(gm, min8p(dd));
    }
    gmin[g] = gm;
  }

  // ---- T = 16th-smallest of the query's 64 group-mins (FMA metric) ----
  float s[16];
  {
    float g8[NG];
#pragma unroll
    for (int g = 0; g < NG; g++) g8[g] = gmin[g];
    SORT8(g8)
#pragma unroll
    for (int j = 0; j < 8; j++) s[j] = g8[j];
#pragma unroll
    for (int j = 8; j < 16; j++) s[j] = 3.0e38f;
  }
#pragma unroll
  for (int mask = 1; mask <= 4; mask <<= 1) {
    float B[16];
#pragma unroll
    for (int j = 0; j < 16; j++) B[j] = __shfl_xor(s[j], mask, 64);
    float L[16];
#pragma unroll
    for (int j = 0; j < 16; j++) L[j] = fminf(s[j], B[15 - j]);
    BITONIC16(L)
#pragma unroll
    for (int j = 0; j < 16; j++) s[j] = L[j];
  }
  // inflate: absorbs FMA-vs-exact rounding skew (proof: any exact-top-16
  // point has dFMA <= T*(1+3*4ulp) << T*(1+4e-6)). Superset preserved.
  const float T = s[15] * (1.0f + 4e-6f);

  // ---- per-lane 8-bit pass mask ----
  unsigned m8 = 0;
#pragma unroll
  for (int g = 0; g < NG; g++) m8 |= (gmin[g] <= T) ? (1u << g) : 0u;

  // ---- butterfly-OR across the query's 8 lanes -> 64-bit group mask ----
  unsigned lo = (part < 4) ? (m8 << (8 * part)) : 0u;
  unsigned hi = (part >= 4) ? (m8 << (8 * (part - 4))) : 0u;
#pragma unroll
  for (int mk = 1; mk <= 4; mk <<= 1) {
    lo |= __shfl_xor(lo, mk, 64);
    hi |= __shfl_xor(hi, mk, 64);
  }
  const unsigned long long vm = ((unsigned long long)hi << 32) | lo;

  // ---- round-robin: k-th set bit -> lane (k & 7) ----
  unsigned long long mym = 0ull;
  {
    unsigned long long m = vm;
    int cnt = 0;
    while (m) {
      const unsigned long long lb = m & (0ull - m);
      if ((cnt & 7) == part) mym |= lb;
      m ^= lb;
      cnt++;
    }
  }

  // ---- pass 2: scan assigned groups; batched slot reservation.
  //      All writes/atomics hit only this query's row -> intra-wave. ----
  while (mym) {
    const int gid = __ffsll(mym) - 1;
    mym &= mym - 1;
    const int cb = (gid >> 3) * CHUNK;
    const int goff = gid & 7;
    const int ib = (gid >> 3) * PPT + goff * 32;
#pragma unroll
    for (int bb = 0; bb < 4; bb++) {
      const int B = goff * 4 + bb;
      const int BS = B ^ (B >> 2);
      f2 dd[4];
      dist8f(px, py, pz, cb + BS * 8, qx, qy, qz, dd);
      if (min8p(dd) <= T) {
        unsigned am = 0;
#pragma unroll
        for (int k = 0; k < 4; k++) {
          am |= (dd[k].x <= T) ? (1u << (2 * k)) : 0u;
          am |= (dd[k].y <= T) ? (1u << (2 * k + 1)) : 0u;
        }
        int pos = atomicAdd(&ccnt[ql], __popc(am));
        while (am) {
          const int k = __ffs(am) - 1;
          am &= am - 1;
          if (pos < CAP)
            cand[ql * CSTR + pos] = (unsigned short)(ib + bb * 8 + k);
          pos++;
        }
      }
    }
  }
  // NO barrier: phase 3 reads only this wave's writes (in-order per wave)

  // ---- phase 3: exact top-16 (d2rn keys), 8-lane parallel ----
  {
    const int cnt = ccnt[ql];
    if (cnt <= CAP) {
      unsigned long long kb8[8];
      // gather this lane's strided candidates: part, part+8, ...
#pragma unroll
      for (int i = 0; i < 8; i++) {
        const int c = part + 8 * i;
        unsigned long long kk = ~0ULL;
        if (c < cnt) {
          const int idx = cand[ql * CSTR + c];
          const int slot = slotOf(idx);
          const float d2 = d2rn(qx, qy, qz, px[slot], py[slot], pz[slot]);
          kk = ((unsigned long long)__float_as_uint(d2) << 32) | (unsigned)idx;
        }
        kb8[i] = kk;
      }
      SORT8U(kb8)

      // round 1 (XOR 1): pair merge -> sorted-16 per lane pair
      {
        unsigned long long bb[8];
#pragma unroll
        for (int j = 0; j < 8; j++) bb[j] = __shfl_xor(kb8[7 - j], 1, 64);
        if (part & 1) {
#pragma unroll
          for (int j = 0; j < 8; j++)
            kb8[j] = (kb8[j] < bb[j]) ? bb[j] : kb8[j];
        } else {
#pragma unroll
          for (int j = 0; j < 8; j++)
            kb8[j] = (kb8[j] < bb[j]) ? kb8[j] : bb[j];
        }
        BSORT8U(kb8)
      }

      // rounds 2,3 (XOR 3 then XOR 5): merge sorted-16s, keep top-16
#pragma unroll
      for (int r = 0; r < 2; r++) {
        const int xm = r ? 5 : 3;
        unsigned long long bb[8];
#pragma unroll
        for (int j = 0; j < 8; j++) bb[j] = __shfl_xor(kb8[7 - j], xm, 64);
#pragma unroll
        for (int j = 0; j < 8; j++)
          kb8[j] = (kb8[j] < bb[j]) ? kb8[j] : bb[j];
#pragma unroll
        for (int j = 0; j < 8; j++) bb[j] = __shfl_xor(kb8[j], 1, 64);
        if (part & 1) {
#pragma unroll
          for (int j = 0; j < 8; j++)
            kb8[j] = (kb8[j] < bb[j]) ? bb[j] : kb8[j];
        } else {
#pragma unroll
          for (int j = 0; j < 8; j++)
            kb8[j] = (kb8[j] < bb[j]) ? kb8[j] : bb[j];
        }
        BSORT8U(kb8)
      }

      // final sorted-16: even lane holds ranks 0-7, odd lane ranks 8-15
      if (part < 2) {
#pragma unroll
        for (int j = 0; j < 8; j++)
          cand[ql * CSTR + part * 8 + j] = (unsigned short)(unsigned)kb8[j];
      }
    } else if (part == 0) {
      // overflow fallback (astronomically rare): serial exact scan
      unsigned long long kb[NK];
#pragma unroll
      for (int j = 0; j < NK; j++) kb[j] = ~0ULL;
      for (int i = 0; i < NN; i++) {
        const int slot = slotOf(i);
        const float d2 = d2rn(qx, qy, qz, px[slot], py[slot], pz[slot]);
        unsigned long long kk =
            ((unsigned long long)__float_as_uint(d2) << 32) | (unsigned)i;
        if (kk < kb[NK - 1]) {
#pragma unroll
          for (int j = 0; j < NK; j++) {
            const bool c2 = kk < kb[j];
            const unsigned long long lo2 = c2 ? kk : kb[j];
            const unsigned long long hi2 = c2 ? kb[j] : kk;
            kb[j] = lo2;
            kk = hi2;
          }
        }
      }
#pragma unroll
      for (int j = 0; j < NK; j++)
        cand[ql * CSTR + j] = (unsigned short)(unsigned)kb[j];
    }
  }
  // NO barrier: output reads only this wave's phase-3 writes

  // ---- output: each part lane writes 2 neighbors (6 floats) ----
  float* o = out_knn + ((size_t)(b * NM + q)) * (NK * 3);
#pragma unroll
  for (int jj = 0; jj < 2; jj++) {
    const int j = part * 2 + jj;
    const int i = cand[ql * CSTR + j];
    const int slot = slotOf(i);
    o[3 * j + 0] = px[slot];
    o[3 * j + 1] = py[slot];
    o[3 * j + 2] = pz[slot];
  }
}

// ---------------------------------------------------------------------------
extern "C" void kernel_launch(void* const* d_in, const int* in_sizes, int n_in,
                              void* d_out, int out_size, void* d_ws,
                              size_t ws_size, hipStream_t stream) {
  const float* xyz      = (const float*)d_in[0];  // [8,2048,3]
  const float* xyz_fp   = (const float*)d_in[1];  // [8,8192,3]
  const float* features = (const float*)d_in[2];  // [8,64,2048]
  const float* W1 = (const float*)d_in[4];        // [64,64]
  const float* b1 = (const float*)d_in[5];        // [64]

  float* out_feats = (float*)d_out;                       // 8*2048*64
  float* out_knn   = out_feats + (size_t)NB * NN * NC;    // 8*8192*16*3
  float* out_x     = out_knn + (size_t)NB * NM * NK * 3;  // 8*2048*64

  fused_kernel<<<dim3(KB + FB, NB), 256, 0, stream>>>(
      features, W1, b1, out_feats, out_x, xyz, xyz_fp, out_knn);
}